// Round 13
// baseline (1465.371 us; speedup 1.0000x reference)
//
#include <hip/hip_runtime.h>
#include <math.h>

#define HH 256
#define GG 1024
#define LL 48
#define NNODES 49152   // G*L
#define NEDGES 98304   // 2*N
#define SB 256.0f      // weight-side scale 2^8
#define DSB 0.00390625f // 2^-8

typedef _Float16 f16;
typedef __attribute__((ext_vector_type(8))) _Float16 f16x8;
typedef __attribute__((ext_vector_type(4))) float f32x4;

#define MFMA16(a, b, c) __builtin_amdgcn_mfma_f32_16x16x32_f16(a, b, c, 0, 0, 0)

__device__ inline float sc_from_max(float m) {
    if (!(m > 0.f)) return 1.0f;
    return ldexpf(1.0f, 13 - ilogbf(m));   // m*sc in [2^13, 2^14)
}

// ---------------------------------------------------------------------------
// CSR build (verified round 2-12)
// ---------------------------------------------------------------------------
__global__ void csr_count(const int* __restrict__ row, int* __restrict__ counts)
{
    int e = blockIdx.x * 256 + threadIdx.x;
    if (e < NEDGES) atomicAdd(&counts[row[e]], 1);
}

__global__ __launch_bounds__(1024) void scan_offsets(const int* __restrict__ counts,
                                                     int* __restrict__ offsets)
{
    __shared__ int tsum[1024];
    const int tid = threadIdx.x;
    const int base = tid * 48;
    int s = 0;
    for (int i = 0; i < 48; i++) s += counts[base + i];
    tsum[tid] = s;
    __syncthreads();
    for (int off = 1; off < 1024; off <<= 1) {
        int v = (tid >= off) ? tsum[tid - off] : 0;
        __syncthreads();
        tsum[tid] += v;
        __syncthreads();
    }
    int run = (tid == 0) ? 0 : tsum[tid - 1];
    for (int i = 0; i < 48; i++) { offsets[base + i] = run; run += counts[base + i]; }
    if (tid == 1023) offsets[NNODES] = run;
}

__global__ void csr_fill(const int* __restrict__ row, const int* __restrict__ offsets,
                         int* __restrict__ cursor, int* __restrict__ elist)
{
    int e = blockIdx.x * 256 + threadIdx.x;
    if (e < NEDGES) {
        int r = row[e];
        int p = atomicAdd(&cursor[r], 1);
        elist[offsets[r] + p] = e;
    }
}

__global__ void prep_graphs(const int* __restrict__ batch, int* __restrict__ starts,
                            int* __restrict__ gcnt)
{
    int i = blockIdx.x * 256 + threadIdx.x;
    if (i < NNODES) {
        int b = batch[i];
        atomicAdd(&gcnt[b], 1);
        if (i == 0 || batch[i - 1] != b) starts[b] = i;
    }
}

__global__ void rowscale(const float* __restrict__ A, int K, float* __restrict__ sc)
{
    int m = blockIdx.x, ln = threadIdx.x;
    float v = 0.f;
    for (int k = ln; k < K; k += 64) v = fmaxf(v, fabsf(A[(size_t)m * K + k]));
    for (int s = 32; s; s >>= 1) v = fmaxf(v, __shfl_xor(v, s));
    if (ln == 0) sc[m] = sc_from_max(v);
}

// merged weight prep (verified round 10-12)
__global__ void prep_wT_all(const float* __restrict__ w_atom, const float* __restrict__ w_bond,
                            const float* __restrict__ conv_w, const float* __restrict__ w_lin,
                            const float* __restrict__ w_out,
                            f16* __restrict__ watomH, f16* __restrict__ watomL,
                            f16* __restrict__ wbondH, f16* __restrict__ wbondL,
                            f16* __restrict__ convH0, f16* __restrict__ convL0,
                            f16* __restrict__ convH1, f16* __restrict__ convL1,
                            f16* __restrict__ convH2, f16* __restrict__ convL2,
                            f16* __restrict__ wlinH, f16* __restrict__ wlinL,
                            f16* __restrict__ woutH, f16* __restrict__ woutL)
{
    int idx = blockIdx.x * 256 + threadIdx.x;
    int krow = idx >> 8, n = idx & 255;
    const float* src; f16* oH; f16* oL; int k;
    if (krow < 128)       { src = w_atom;           oH = watomH; oL = watomL; k = krow; }
    else if (krow < 192)  { src = w_bond;           oH = wbondH; oL = wbondL; k = krow - 128; }
    else if (krow < 448)  { src = conv_w;           oH = convH0; oL = convL0; k = krow - 192; }
    else if (krow < 704)  { src = conv_w + 65536;   oH = convH1; oL = convL1; k = krow - 448; }
    else if (krow < 960)  { src = conv_w + 131072;  oH = convH2; oL = convL2; k = krow - 704; }
    else if (krow < 1728) { src = w_lin;            oH = wlinH;  oL = wlinL;  k = krow - 960; }
    else                  { src = w_out;            oH = woutH;  oL = woutL;  k = krow - 1728; }
    float v = src[(size_t)k * 256 + n] * SB;
    f16 h = (f16)v;
    size_t o = ((size_t)(k >> 5) * 256 + n) * 32 + (k & 31);
    oH[o] = h;
    oL[o] = (f16)(v - (float)h);
}

// GRU weight prep (verified round 2-12)
__global__ void prep_gruW(const float* __restrict__ w_ih, const float* __restrict__ w_hh,
                          const float* __restrict__ b_ih, const float* __restrict__ b_hh,
                          f16* __restrict__ BgH, f16* __restrict__ BgL,
                          float* __restrict__ bias4)
{
    int idx = blockIdx.x * 256 + threadIdx.x;   // 2*512*1024
    int d = idx >> 19;
    int rem = idx & 524287;
    int k = rem >> 10;
    int col = rem & 1023;
    int jj = col >> 2, s = col & 3;
    const float* Wi = w_ih + (size_t)d * 768 * 256;
    const float* Wh = w_hh + (size_t)d * 768 * 256;
    float v;
    if (s == 0)      v = (k < 256) ? Wi[(size_t)jj * 256 + k]         : Wh[(size_t)jj * 256 + (k - 256)];
    else if (s == 1) v = (k < 256) ? Wi[(size_t)(256 + jj) * 256 + k] : Wh[(size_t)(256 + jj) * 256 + (k - 256)];
    else if (s == 2) v = (k < 256) ? Wi[(size_t)(512 + jj) * 256 + k] : 0.f;
    else             v = (k < 256) ? 0.f : Wh[(size_t)(512 + jj) * 256 + (k - 256)];
    v *= SB;
    f16 h = (f16)v;
    size_t o = ((size_t)(d * 16 + (k >> 5)) * 1024 + col) * 32 + (k & 31);
    BgH[o] = h;
    BgL[o] = (f16)(v - (float)h);
    if (k == 0) {
        const float* bi = b_ih + d * 768;
        const float* bh = b_hh + d * 768;
        float bv;
        if (s == 0)      bv = bi[jj] + bh[jj];
        else if (s == 1) bv = bi[256 + jj] + bh[256 + jj];
        else if (s == 2) bv = bi[512 + jj];
        else             bv = bh[512 + jj];
        bias4[d * 1024 + col] = bv;
    }
}

// booster v2 (verified round 10-12)
__global__ void booster(const float* __restrict__ hb_lo, const float* __restrict__ hb_hi,
                        const float* __restrict__ atom_in, float* __restrict__ out,
                        const int* __restrict__ offsets, const int* __restrict__ elist,
                        float* __restrict__ scOut)
{
    const int wv = threadIdx.x >> 6;
    const int n = blockIdx.x * 4 + wv;
    const int ln = threadIdx.x & 63;
    const int b0 = offsets[n], b1 = offsets[n + 1];
    float4 s = {0.f, 0.f, 0.f, 0.f}, m = {0.f, 0.f, 0.f, 0.f};
    for (int p = b0; p < b1; p++) {
        int e = elist[p];
        const float* hb = (e < NNODES) ? (hb_lo + (size_t)e * HH)
                                       : (hb_hi + (size_t)(e - NNODES) * HH);
        float4 v = *(const float4*)(hb + ln * 4);
        s.x += v.x; s.y += v.y; s.z += v.z; s.w += v.w;
        m.x = fmaxf(m.x, v.x); m.y = fmaxf(m.y, v.y);
        m.z = fmaxf(m.z, v.z); m.w = fmaxf(m.w, v.w);
    }
    float4 a = *(const float4*)(atom_in + (size_t)n * HH + ln * 4);
    float4 o;
    o.x = a.x + s.x * m.x; o.y = a.y + s.y * m.y;
    o.z = a.z + s.z * m.z; o.w = a.w + s.w * m.w;
    *(float4*)(out + (size_t)n * HH + ln * 4) = o;
    float v = fmaxf(fmaxf(fabsf(o.x), fabsf(o.y)), fmaxf(fabsf(o.z), fabsf(o.w)));
    for (int t = 32; t; t >>= 1) v = fmaxf(v, __shfl_xor(v, t));
    if (ln == 0) scOut[n] = sc_from_max(v);
}

// h0_init v2 (verified round 10-12)
__global__ void h0_init(const float* __restrict__ h, const int* __restrict__ starts,
                        const int* __restrict__ gcnt, float* __restrict__ hid0,
                        float* __restrict__ scG)
{
    const int wv = threadIdx.x >> 6;
    const int g = blockIdx.x * 4 + wv;
    const int ln = threadIdx.x & 63;
    const int st = starts[g], cn = gcnt[g];
    float4 m = {-INFINITY, -INFINITY, -INFINITY, -INFINITY};
    float4 am = {0.f, 0.f, 0.f, 0.f};
    for (int i = 0; i < cn; i++) {
        float4 v = *(const float4*)(h + (size_t)(st + i) * HH + ln * 4);
        m.x = fmaxf(m.x, v.x); m.y = fmaxf(m.y, v.y);
        m.z = fmaxf(m.z, v.z); m.w = fmaxf(m.w, v.w);
        am.x = fmaxf(am.x, fabsf(v.x)); am.y = fmaxf(am.y, fabsf(v.y));
        am.z = fmaxf(am.z, fabsf(v.z)); am.w = fmaxf(am.w, fabsf(v.w));
    }
    if (cn == 0) { m.x = m.y = m.z = m.w = 0.f; }
    *(float4*)(hid0 + (size_t)g * HH + ln * 4) = m;
    *(float4*)(hid0 + (size_t)GG * HH + (size_t)g * HH + ln * 4) = m;
    float a = fmaxf(fmaxf(am.x, am.y), fmaxf(am.z, am.w));
    for (int t = 32; t; t >>= 1) a = fmaxf(a, __shfl_xor(a, t));
    if (ln == 0) scG[g] = sc_from_max(fmaxf(a + 0.07f, 1.0f));
}

// msgP v2 (verified round 12): float4 per thread, 4 graphs per block
__global__ void build_msgP(const float* __restrict__ h, const float* __restrict__ gbias,
                           const int* __restrict__ starts, const int* __restrict__ gcnt,
                           float* __restrict__ msgP)
{
    const int l = blockIdx.x;
    const int g = blockIdx.y * 4 + (threadIdx.x >> 6);
    const int q = threadIdx.x & 63;
    float4 v = {0.f, 0.f, 0.f, 0.f};
    if (l < gcnt[g]) {
        float4 hv = *(const float4*)(h + (size_t)(starts[g] + l) * HH + q * 4);
        float4 bv = *(const float4*)(gbias + q * 4);
        v.x = fmaxf(hv.x + bv.x, 0.f); v.y = fmaxf(hv.y + bv.y, 0.f);
        v.z = fmaxf(hv.z + bv.z, 0.f); v.w = fmaxf(hv.w + bv.w, 0.f);
    }
    *(float4*)(msgP + ((size_t)l * GG + g) * HH + q * 4) = v;
}

// ---------------------------------------------------------------------------
// A-tile element loaders (8 consecutive k of one row)
// ---------------------------------------------------------------------------
template<int MODE>
__device__ __forceinline__ void gemmLoadA(const float* __restrict__ A,
    const float* __restrict__ S0, const float* __restrict__ S1,
    const float* __restrict__ S2, int rI, int cI, int row, int K, int k,
    float va[8])
{
    if constexpr (MODE == 0) {
        const float* p = A + (size_t)row * K + k;
        float4 v0 = *(const float4*)p, v1 = *(const float4*)(p + 4);
        va[0]=v0.x; va[1]=v0.y; va[2]=v0.z; va[3]=v0.w;
        va[4]=v1.x; va[5]=v1.y; va[6]=v1.z; va[7]=v1.w;
    } else if constexpr (MODE == 1) {
        const float* pa = S0 + (size_t)rI * HH + k;
        const float* pb = S1 + (size_t)cI * HH + k;
        float4 a0 = *(const float4*)pa, a1 = *(const float4*)(pa + 4);
        float4 b0 = *(const float4*)pb, b1 = *(const float4*)(pb + 4);
        va[0]=a0.x-b0.x; va[1]=a0.y-b0.y; va[2]=a0.z-b0.z; va[3]=a0.w-b0.w;
        va[4]=a1.x-b1.x; va[5]=a1.y-b1.y; va[6]=a1.z-b1.z; va[7]=a1.w-b1.w;
    } else if constexpr (MODE == 2) {
        const float* S = (k < 256) ? S0 : ((k < 512) ? S1 : S2);
        const float* p = S + (size_t)row * HH + (k & 255);
        float4 v0 = *(const float4*)p, v1 = *(const float4*)(p + 4);
        va[0]=v0.x; va[1]=v0.y; va[2]=v0.z; va[3]=v0.w;
        va[4]=v1.x; va[5]=v1.y; va[6]=v1.z; va[7]=v1.w;
    } else {
        const float* S = (k < 256) ? S0 : S1;
        const float* p = S + (size_t)row * HH + (k & 255);
        float4 v0 = *(const float4*)p, v1 = *(const float4*)(p + 4);
        va[0]=v0.x; va[1]=v0.y; va[2]=v0.z; va[3]=v0.w;
        va[4]=v1.x; va[5]=v1.y; va[6]=v1.z; va[7]=v1.w;
    }
}

// ---------------------------------------------------------------------------
// f16 split MFMA GEMM v5: 512 threads, 128x256 tile, 8 waves (2 row-halves x
// 4 col-quarters). Schedule = round-11 v3 (1-deep reg-B, LDS-dbuf A, one
// barrier/iter). Per-element MFMA operand order identical -> bit-identical.
// ---------------------------------------------------------------------------
template<int MODE, bool RELU, bool SPLITC, bool WSCALE, int NX>
__global__ __launch_bounds__(512) void gemm_f16x3(
    const float* __restrict__ A,
    const float* __restrict__ S0, const float* __restrict__ S1, const float* __restrict__ S2,
    const int* __restrict__ ridx, const int* __restrict__ cidx,
    const f16* __restrict__ BgH, const f16* __restrict__ BgL,
    const float* __restrict__ bias,
    const float* __restrict__ sc0, const float* __restrict__ sc1, const float* __restrict__ sc2,
    float* __restrict__ Clo, float* __restrict__ Chi,
    float* __restrict__ scOut, int K)
{
    __shared__ __align__(16) f16 AhB[2][128 * 40], AlB[2][128 * 40];
    __shared__ float scL[128];
    __shared__ float rmL[128][4];

    const int tid = threadIdx.x;
    const int m0 = blockIdx.x * 128;
    const int arow = tid >> 2, aoct = tid & 3;           // A: 128 rows x 4 octets
    const int w = tid >> 6;                              // 8 waves
    const int wr = w >> 2, wq = w & 3;                   // row-half, col-quarter
    const int lane = tid & 63, lr = lane & 15, lh = lane >> 4;

    if (tid < 128) {
        float sc;
        if constexpr (MODE == 0) sc = sc0[m0 + tid];
        else if constexpr (MODE == 1) {
            int r = ridx[m0 + tid], cc = cidx[m0 + tid];
            sc = fminf(sc0[r], sc1[cc]) * 0.5f;
        } else if constexpr (MODE == 2) {
            sc = fminf(fminf(sc0[m0 + tid], sc1[m0 + tid]), sc2[m0 + tid]);
        } else {
            sc = sc0[cidx[m0 + tid]];
        }
        scL[tid] = sc;
    }
    int rI = 0, cI = 0;
    if constexpr (MODE == 1) { rI = ridx[m0 + arow]; cI = cidx[m0 + arow]; }
    __syncthreads();
    const float myS = scL[arow];
    const int nIter = K >> 5;

    // ---- prologue: A(0) -> buf0; B(0) -> regs
    {
        float va0[8];
        gemmLoadA<MODE>(A, S0, S1, S2, rI, cI, m0 + arow, K, aoct * 8, va0);
        f16x8 hi, lo;
#pragma unroll
        for (int e = 0; e < 8; e++) {
            float a = va0[e] * myS;
            f16 h = (f16)a;
            hi[e] = h;
            if constexpr (NX == 3) lo[e] = (f16)(a - (float)h);
        }
        *(f16x8*)&AhB[0][arow * 40 + aoct * 8] = hi;
        if constexpr (NX == 3) *(f16x8*)&AlB[0][arow * 40 + aoct * 8] = lo;
    }
    f16x8 fbh[4], fbl[4];
#pragma unroll
    for (int j = 0; j < 4; j++) {
        size_t o = (size_t)(wq * 64 + j * 16 + lr) * 32 + lh * 8;
        fbh[j] = *(const f16x8*)(BgH + o);
        if constexpr (NX == 3) fbl[j] = *(const f16x8*)(BgL + o);
    }
    __syncthreads();

    f32x4 acc[4][4] = {};
    for (int kb = 0; kb < nIter; kb++) {
        const f16* AhC = AhB[kb & 1];
        const f16* AlC = AlB[kb & 1];
        // issue next-iter A and B loads
        float va[8];
        f16x8 nbh[4], nbl[4];
        if (kb + 1 < nIter) {
            gemmLoadA<MODE>(A, S0, S1, S2, rI, cI, m0 + arow, K, (kb + 1) * 32 + aoct * 8, va);
#pragma unroll
            for (int j = 0; j < 4; j++) {
                size_t o = ((size_t)(kb + 1) * 256 + (wq * 64 + j * 16 + lr)) * 32 + lh * 8;
                nbh[j] = *(const f16x8*)(BgH + o);
                if constexpr (NX == 3) nbl[j] = *(const f16x8*)(BgL + o);
            }
        }
        // MFMA on current iter — round-6 operand order
        f16x8 fah[4], fal[4];
#pragma unroll
        for (int i = 0; i < 4; i++) {
            fah[i] = *(const f16x8*)&AhC[(wr * 64 + i * 16 + lr) * 40 + lh * 8];
            if constexpr (NX == 3) fal[i] = *(const f16x8*)&AlC[(wr * 64 + i * 16 + lr) * 40 + lh * 8];
        }
#pragma unroll
        for (int j = 0; j < 4; j++) {
            if constexpr (NX == 3) {
#pragma unroll
                for (int i = 0; i < 4; i++) {
                    acc[i][j] = MFMA16(fah[i], fbh[j], acc[i][j]);
                    acc[i][j] = MFMA16(fah[i], fbl[j], acc[i][j]);
                    acc[i][j] = MFMA16(fal[i], fbh[j], acc[i][j]);
                }
            } else {
#pragma unroll
                for (int i = 0; i < 4; i++)
                    acc[i][j] = MFMA16(fah[i], fbh[j], acc[i][j]);
            }
        }
        // convert+store next A; roll B regs
        if (kb + 1 < nIter) {
            f16x8 hi, lo;
#pragma unroll
            for (int e = 0; e < 8; e++) {
                float a = va[e] * myS;
                f16 h = (f16)a;
                hi[e] = h;
                if constexpr (NX == 3) lo[e] = (f16)(a - (float)h);
            }
            f16* AhN = AhB[(kb + 1) & 1];
            f16* AlN = AlB[(kb + 1) & 1];
            *(f16x8*)&AhN[arow * 40 + aoct * 8] = hi;
            if constexpr (NX == 3) *(f16x8*)&AlN[arow * 40 + aoct * 8] = lo;
#pragma unroll
            for (int j = 0; j < 4; j++) {
                fbh[j] = nbh[j];
                if constexpr (NX == 3) fbl[j] = nbl[j];
            }
        }
        __syncthreads();
    }

    float rm[4][4];
#pragma unroll
    for (int i = 0; i < 4; i++)
#pragma unroll
        for (int e = 0; e < 4; e++) rm[i][e] = 0.f;
#pragma unroll
    for (int i = 0; i < 4; i++) {
#pragma unroll
        for (int e = 0; e < 4; e++) {
            int ml = wr * 64 + i * 16 + lh * 4 + e;
            int m = m0 + ml;
            float inv = DSB / scL[ml];
            float* Cb;
            if constexpr (SPLITC)
                Cb = (m < NNODES) ? (Clo + (size_t)m * HH) : (Chi + (size_t)(m - NNODES) * HH);
            else
                Cb = Clo + (size_t)m * HH;
#pragma unroll
            for (int j = 0; j < 4; j++) {
                int n = wq * 64 + j * 16 + lr;
                float v = acc[i][j][e] * inv + bias[n];
                if constexpr (RELU) v = fmaxf(v, 0.f);
                Cb[n] = v;
                if constexpr (WSCALE) rm[i][e] = fmaxf(rm[i][e], fabsf(v));
            }
        }
    }
    if constexpr (WSCALE) {
#pragma unroll
        for (int i = 0; i < 4; i++)
#pragma unroll
            for (int e = 0; e < 4; e++) {
                float v = rm[i][e];
                v = fmaxf(v, __shfl_xor(v, 1));
                v = fmaxf(v, __shfl_xor(v, 2));
                v = fmaxf(v, __shfl_xor(v, 4));
                v = fmaxf(v, __shfl_xor(v, 8));
                if (lr == 0) rmL[wr * 64 + i * 16 + lh * 4 + e][wq] = v;
            }
        __syncthreads();
        if (tid < 128)
            scOut[m0 + tid] = sc_from_max(fmaxf(fmaxf(rmL[tid][0], rmL[tid][1]),
                                                fmaxf(rmL[tid][2], rmL[tid][3])));
    }
}

// ---------------------------------------------------------------------------
// GRU step v8 (verified round 12): 512 threads, 64g x 128c, grid 256,
// 2-deep A prefetch, reg-dbuf B, LDS-dbuf A, 1 barrier/window.
// ---------------------------------------------------------------------------
__global__ __launch_bounds__(512) void gru_step_f16(
    const float* __restrict__ msgP, const f16* __restrict__ BgH, const f16* __restrict__ BgL,
    const float* __restrict__ bias4, const float* __restrict__ hidC, float* __restrict__ hidN,
    const float* __restrict__ scG, const int* __restrict__ starts, const int* __restrict__ gcnt,
    float* __restrict__ outF, float* __restrict__ outB, int t)
{
    __shared__ __align__(16) char smemraw[36864];
    float* Cs = (float*)smemraw;
    __shared__ float scL[64];

    const int tid = threadIdx.x;
    const int id = blockIdx.x;
    const int c = id & 7, d = (id >> 3) & 1, gt = id >> 4;
    const int g0 = gt * 64;
    const int l = d ? (LL - 1 - t) : t;
    const float* hidCd = hidC + (size_t)d * GG * HH;
    float* hidNd = hidN + (size_t)d * GG * HH;

    if (tid < 64) scL[tid] = scG[g0 + tid];
    __syncthreads();

    const int arow = tid >> 3, akoct = tid & 7;
    const float myS = scL[arow];
    const int w = tid >> 6;
    const int wg = w >> 2, wc = w & 3;
    const int lane = tid & 63, lr = lane & 15, lh = lane >> 4;

    f16* Ah0 = (f16*)smemraw;
    f16* Al0 = Ah0 + 4608;
    f16* Ah1 = Al0 + 4608;
    f16* Al1 = Ah1 + 4608;

    {
        const float* p = msgP + ((size_t)l * GG + g0 + arow) * HH + akoct * 8;
        float4 v0 = *(const float4*)p, v1 = *(const float4*)(p + 4);
        float va0[8] = {v0.x, v0.y, v0.z, v0.w, v1.x, v1.y, v1.z, v1.w};
        f16x8 hi, lo;
#pragma unroll
        for (int e = 0; e < 8; e++) {
            float a = va0[e] * myS;
            f16 h = (f16)a;
            hi[e] = h;
            lo[e] = (f16)(a - (float)h);
        }
        *(f16x8*)&Ah0[arow * 72 + akoct * 8] = hi;
        *(f16x8*)&Al0[arow * 72 + akoct * 8] = lo;
    }
    float va[8];
    {
        const float* p = msgP + ((size_t)l * GG + g0 + arow) * HH + 64 + akoct * 8;
        float4 v0 = *(const float4*)p, v1 = *(const float4*)(p + 4);
        va[0]=v0.x; va[1]=v0.y; va[2]=v0.z; va[3]=v0.w;
        va[4]=v1.x; va[5]=v1.y; va[6]=v1.z; va[7]=v1.w;
    }
    f16x8 fbh[2][2], fbl[2][2];
#pragma unroll
    for (int ks = 0; ks < 2; ks++) {
        size_t kbase = (size_t)(d * 16 + ks) * 1024;
#pragma unroll
        for (int j = 0; j < 2; j++) {
            size_t o = (kbase + (c * 128 + wc * 32 + j * 16 + lr)) * 32 + lh * 8;
            fbh[ks][j] = *(const f16x8*)(BgH + o);
            fbl[ks][j] = *(const f16x8*)(BgL + o);
        }
    }
    __syncthreads();

    f32x4 acc[2][2] = {};
#pragma unroll
    for (int win = 0; win < 8; win++) {
        f16* AhC = (win & 1) ? Ah1 : Ah0;
        f16* AlC = (win & 1) ? Al1 : Al0;
        f16* AhN = (win & 1) ? Ah0 : Ah1;
        f16* AlN = (win & 1) ? Al0 : Al1;

        float nva[8];
        if (win + 2 < 8) {
            int k = (win + 2) * 64 + akoct * 8;
            const float* p = (k < 256)
                ? msgP + ((size_t)l * GG + g0 + arow) * HH + k
                : hidCd + (size_t)(g0 + arow) * HH + (k - 256);
            float4 v0 = *(const float4*)p, v1 = *(const float4*)(p + 4);
            nva[0]=v0.x; nva[1]=v0.y; nva[2]=v0.z; nva[3]=v0.w;
            nva[4]=v1.x; nva[5]=v1.y; nva[6]=v1.z; nva[7]=v1.w;
        }
        f16x8 nbh[2][2], nbl[2][2];
        if (win + 1 < 8) {
#pragma unroll
            for (int ks = 0; ks < 2; ks++) {
                size_t kbase = (size_t)(d * 16 + (win + 1) * 2 + ks) * 1024;
#pragma unroll
                for (int j = 0; j < 2; j++) {
                    size_t o = (kbase + (c * 128 + wc * 32 + j * 16 + lr)) * 32 + lh * 8;
                    nbh[ks][j] = *(const f16x8*)(BgH + o);
                    nbl[ks][j] = *(const f16x8*)(BgL + o);
                }
            }
        }
#pragma unroll
        for (int ks = 0; ks < 2; ks++) {
            f16x8 fah[2], fal[2];
#pragma unroll
            for (int i = 0; i < 2; i++) {
                fah[i] = *(const f16x8*)&AhC[(wg * 32 + i * 16 + lr) * 72 + ks * 32 + lh * 8];
                fal[i] = *(const f16x8*)&AlC[(wg * 32 + i * 16 + lr) * 72 + ks * 32 + lh * 8];
            }
#pragma unroll
            for (int j = 0; j < 2; j++) {
#pragma unroll
                for (int i = 0; i < 2; i++) {
                    acc[i][j] = MFMA16(fah[i], fbh[ks][j], acc[i][j]);
                    acc[i][j] = MFMA16(fah[i], fbl[ks][j], acc[i][j]);
                    acc[i][j] = MFMA16(fal[i], fbh[ks][j], acc[i][j]);
                }
            }
        }
        if (win + 1 < 8) {
            f16x8 hi, lo;
#pragma unroll
            for (int e = 0; e < 8; e++) {
                float a = va[e] * myS;
                f16 h = (f16)a;
                hi[e] = h;
                lo[e] = (f16)(a - (float)h);
            }
            *(f16x8*)&AhN[arow * 72 + akoct * 8] = hi;
            *(f16x8*)&AlN[arow * 72 + akoct * 8] = lo;
        }
        if (win + 2 < 8) {
#pragma unroll
            for (int e = 0; e < 8; e++) va[e] = nva[e];
        }
        if (win + 1 < 8) {
#pragma unroll
            for (int ks = 0; ks < 2; ks++)
#pragma unroll
                for (int j = 0; j < 2; j++) {
                    fbh[ks][j] = nbh[ks][j];
                    fbl[ks][j] = nbl[ks][j];
                }
        }
        __syncthreads();
    }

#pragma unroll
    for (int i = 0; i < 2; i++) {
#pragma unroll
        for (int e = 0; e < 4; e++) {
            int ml = wg * 32 + i * 16 + lh * 4 + e;
            float inv = DSB / scL[ml];
#pragma unroll
            for (int j = 0; j < 2; j++)
                Cs[ml * 132 + wc * 32 + j * 16 + lr] = acc[i][j][e] * inv;
        }
    }
    __syncthreads();

    const float* b4 = bias4 + d * 1024;
    const int jl = tid & 31;
    const int J  = c * 32 + jl;
    const int gbase = (tid >> 5) * 4;
    const float bb0 = b4[4 * J + 0], bb1 = b4[4 * J + 1];
    const float bb2 = b4[4 * J + 2], bb3 = b4[4 * J + 3];
    float* o = d ? outB : outF;
#pragma unroll
    for (int i = 0; i < 4; i++) {
        int gl = gbase + i;
        int g = g0 + gl;
        f32x4 gv = *(const f32x4*)&Cs[gl * 132 + jl * 4];
        float r = 1.f / (1.f + expf(-(gv[0] + bb0)));
        float z = 1.f / (1.f + expf(-(gv[1] + bb1)));
        float nn = tanhf(gv[2] + bb2 + r * (gv[3] + bb3));
        float hp = hidCd[(size_t)g * HH + J];
        float hnew = (1.f - z) * nn + z * hp;
        hidNd[(size_t)g * HH + J] = hnew;
        if (l < gcnt[g]) o[(size_t)(starts[g] + l) * HH + J] = hnew;
    }
}

__global__ void fill_sentinel(float* __restrict__ out, float v)
{
    size_t idx = (size_t)blockIdx.x * 256 + threadIdx.x;
    out[idx] = v;
}

// ---------------------------------------------------------------------------
// Workspace layout identical to round 3-12 (verified).
// ---------------------------------------------------------------------------
extern "C" void kernel_launch(void* const* d_in, const int* in_sizes, int n_in,
                              void* d_out, int out_size, void* d_ws, size_t ws_size,
                              hipStream_t stream)
{
    (void)in_sizes; (void)n_in; (void)out_size;
    const float* x         = (const float*)d_in[0];
    const float* edge_attr = (const float*)d_in[1];
    const int*   eidx      = (const int*)d_in[2];
    const int*   batch     = (const int*)d_in[3];
    const float* w_atom    = (const float*)d_in[4];
    const float* b_atom    = (const float*)d_in[5];
    const float* w_bond    = (const float*)d_in[6];
    const float* b_bond    = (const float*)d_in[7];
    const float* conv_w    = (const float*)d_in[8];
    const float* conv_b    = (const float*)d_in[9];
    const float* w_lin     = (const float*)d_in[10];
    const float* b_lin     = (const float*)d_in[11];
    const float* gru_bias  = (const float*)d_in[12];
    const float* w_ih      = (const float*)d_in[13];
    const float* w_hh      = (const float*)d_in[14];
    const float* b_ih      = (const float*)d_in[15];
    const float* b_hh      = (const float*)d_in[16];
    const float* w_out     = (const float*)d_in[17];
    const float* b_out     = (const float*)d_in[18];

    const int* row = eidx;
    const int* col = eidx + NEDGES;

    const size_t NH = (size_t)NNODES * HH;

    float* W   = (float*)d_ws;
    float* W0  = W;
    float* W1  = W + NH;
    float* W1h = W + 2 * NH;
    float* W2  = W + 3 * NH;
    float* DO  = (float*)d_out;

    size_t off = 4 * NH;
    int* counts  = (int*)(W + off);      off += NNODES;
    int* cursor  = (int*)(W + off);      off += NNODES;
    int* gcnt    = (int*)(W + off);      off += GG;
    int* starts  = (int*)(W + off);      off += GG;
    int* offsets = (int*)(W + off);      off += NNODES + 1;
    int* elist   = (int*)(W + off);      off += NEDGES;
    float* scX    = W + off;             off += NNODES;
    float* scEA   = W + off;             off += NEDGES;
    float* scHbA  = W + off;             off += NEDGES;
    float* scHbB  = W + off;             off += NEDGES;
    float* scAtom = W + off;             off += NNODES;
    float* scAggr = W + off;             off += NNODES;
    float* scXp   = W + off;             off += NNODES;
    float* scGru  = W + off;             off += GG;
    off = (off + 3) & ~(size_t)3;
    f16* fp = (f16*)(W + off);
    f16* watomH = fp;                     fp += 4 * 256 * 32;
    f16* watomL = fp;                     fp += 4 * 256 * 32;
    f16* wbondH = fp;                     fp += 2 * 256 * 32;
    f16* wbondL = fp;                     fp += 2 * 256 * 32;
    f16* convH[3]; f16* convL[3];
    for (int i = 0; i < 3; i++) { convH[i] = fp; fp += 8 * 256 * 32; convL[i] = fp; fp += 8 * 256 * 32; }
    f16* wlinH = fp;                      fp += 24 * 256 * 32;
    f16* wlinL = fp;                      fp += 24 * 256 * 32;
    f16* woutH = fp;                      fp += 16 * 256 * 32;
    f16* woutL = fp;                      fp += 16 * 256 * 32;

    const size_t NEED = (char*)fp - (char*)d_ws;
    if (ws_size < NEED) {
        fill_sentinel<<<(int)(NH / 256), 256, 0, stream>>>((float*)d_out, (float)ws_size);
        return;
    }

    // d_out overlay (dead between final booster and final GEMM)
    float* hid0  = DO;
    float* hid1  = DO + 2 * (size_t)GG * HH;
    float* bias4 = DO + 4 * (size_t)GG * HH;
    f16* BgH = (f16*)(bias4 + 2048);
    f16* BgL = BgH + (size_t)2 * 16 * 1024 * 32;

    hipMemsetAsync(counts, 0, (size_t)(2 * NNODES + 2 * GG) * sizeof(int), stream);
    prep_graphs<<<(NNODES + 255) / 256, 256, 0, stream>>>(batch, starts, gcnt);
    csr_count<<<(NEDGES + 255) / 256, 256, 0, stream>>>(row, counts);
    scan_offsets<<<1, 1024, 0, stream>>>(counts, offsets);
    csr_fill<<<(NEDGES + 255) / 256, 256, 0, stream>>>(row, offsets, cursor, elist);

    rowscale<<<NNODES, 64, 0, stream>>>(x, 128, scX);
    rowscale<<<NEDGES, 64, 0, stream>>>(edge_attr, 64, scEA);

    prep_wT_all<<<2240, 256, 0, stream>>>(w_atom, w_bond, conv_w, w_lin, w_out,
        watomH, watomL, wbondH, wbondL, convH[0], convL[0], convH[1], convL[1],
        convH[2], convL[2], wlinH, wlinL, woutH, woutL);

    // x_proj = relu(x @ w_atom + b_atom) -> W0, scAtom
    gemm_f16x3<0, true, false, true, 3><<<NNODES / 128, 512, 0, stream>>>(
        x, nullptr, nullptr, nullptr, nullptr, nullptr, watomH, watomL, b_atom,
        scX, nullptr, nullptr, W0, nullptr, scAtom, 128);
    // bondA = relu(edge_attr @ w_bond + b_bond) -> (W1, W1h), scHbA
    gemm_f16x3<0, true, true, true, 3><<<NEDGES / 128, 512, 0, stream>>>(
        edge_attr, nullptr, nullptr, nullptr, nullptr, nullptr, wbondH, wbondL, b_bond,
        scEA, nullptr, nullptr, W1, W1h, scHbA, 64);

    float* cur_lo = W1; float* cur_hi = W1h; float* cur_sc = scHbA;
    float* nxt_lo = W2; float* nxt_hi = DO;  float* nxt_sc = scHbB;
    for (int i = 0; i < 3; i++) {
        booster<<<NNODES / 4, 256, 0, stream>>>(cur_lo, cur_hi, W0, W0, offsets, elist, scAtom);
        gemm_f16x3<1, true, true, true, 3><<<NEDGES / 128, 512, 0, stream>>>(
            nullptr, W0, cur_lo, nullptr, row, col, convH[i], convL[i],
            conv_b + (size_t)i * HH, scAtom, cur_sc, nullptr, nxt_lo, nxt_hi, nxt_sc, 256);
        float* t0 = cur_lo; cur_lo = nxt_lo; nxt_lo = t0;
        float* t1 = cur_hi; cur_hi = nxt_hi; nxt_hi = t1;
        float* t2 = cur_sc; cur_sc = nxt_sc; nxt_sc = t2;
    }
    // aggr = h_atom + booster(bondB) -> W1 (bondA dead)
    booster<<<NNODES / 4, 256, 0, stream>>>(cur_lo, cur_hi, W0, W1, offsets, elist, scAggr);
    // recompute x_proj -> W1h
    gemm_f16x3<0, true, false, true, 3><<<NNODES / 128, 512, 0, stream>>>(
        x, nullptr, nullptr, nullptr, nullptr, nullptr, watomH, watomL, b_atom,
        scX, nullptr, nullptr, W1h, nullptr, scXp, 128);
    // h = concat(aggr, h_atom, x_proj) @ w_lin + b_lin -> W2
    gemm_f16x3<2, false, false, false, 3><<<NNODES / 128, 512, 0, stream>>>(
        nullptr, W1, W0, W1h, nullptr, nullptr, wlinH, wlinL, b_lin,
        scAggr, scAtom, scXp, W2, nullptr, nullptr, 768);

    // GRU prep (DO bond rows dead now)
    h0_init<<<GG / 4, 256, 0, stream>>>(W2, starts, gcnt, hid0, scGru);
    build_msgP<<<dim3(LL, GG / 4), 256, 0, stream>>>(W2, gru_bias, starts, gcnt, W1h);
    prep_gruW<<<(2 * 512 * 1024) / 256, 256, 0, stream>>>(w_ih, w_hh, b_ih, b_hh, BgH, BgL, bias4);

    for (int t = 0; t < LL; t++) {
        float* hc = (t & 1) ? hid1 : hid0;
        float* hx = (t & 1) ? hid0 : hid1;
        gru_step_f16<<<256, 512, 0, stream>>>(W1h, BgH, BgL, bias4, hc, hx,
                                              scGru, starts, gcnt, W0, W1, t);
    }

    // out = relu(concat(outF, outB) @ w_out + b_out), pure f16 (NX=1)
    gemm_f16x3<3, true, false, false, 1><<<NNODES / 128, 512, 0, stream>>>(
        nullptr, W0, W1, nullptr, nullptr, batch, woutH, nullptr, b_out,
        scGru, nullptr, nullptr, (float*)d_out, nullptr, nullptr, 512);
}

// Round 14
// 1373.742 us; speedup vs baseline: 1.0667x; 1.0667x over previous
//
#include <hip/hip_runtime.h>
#include <math.h>

#define HH 256
#define GG 1024
#define LL 48
#define NNODES 49152   // G*L
#define NEDGES 98304   // 2*N
#define SB 256.0f      // weight-side scale 2^8
#define DSB 0.00390625f // 2^-8

typedef _Float16 f16;
typedef __attribute__((ext_vector_type(8))) _Float16 f16x8;
typedef __attribute__((ext_vector_type(4))) float f32x4;

#define MFMA16(a, b, c) __builtin_amdgcn_mfma_f32_16x16x32_f16(a, b, c, 0, 0, 0)

__device__ inline float sc_from_max(float m) {
    if (!(m > 0.f)) return 1.0f;
    return ldexpf(1.0f, 13 - ilogbf(m));   // m*sc in [2^13, 2^14)
}

// ---------------------------------------------------------------------------
// CSR build (verified round 2-13)
// ---------------------------------------------------------------------------
__global__ void csr_count(const int* __restrict__ row, int* __restrict__ counts)
{
    int e = blockIdx.x * 256 + threadIdx.x;
    if (e < NEDGES) atomicAdd(&counts[row[e]], 1);
}

__global__ __launch_bounds__(1024) void scan_offsets(const int* __restrict__ counts,
                                                     int* __restrict__ offsets)
{
    __shared__ int tsum[1024];
    const int tid = threadIdx.x;
    const int base = tid * 48;
    int s = 0;
    for (int i = 0; i < 48; i++) s += counts[base + i];
    tsum[tid] = s;
    __syncthreads();
    for (int off = 1; off < 1024; off <<= 1) {
        int v = (tid >= off) ? tsum[tid - off] : 0;
        __syncthreads();
        tsum[tid] += v;
        __syncthreads();
    }
    int run = (tid == 0) ? 0 : tsum[tid - 1];
    for (int i = 0; i < 48; i++) { offsets[base + i] = run; run += counts[base + i]; }
    if (tid == 1023) offsets[NNODES] = run;
}

__global__ void csr_fill(const int* __restrict__ row, const int* __restrict__ offsets,
                         int* __restrict__ cursor, int* __restrict__ elist)
{
    int e = blockIdx.x * 256 + threadIdx.x;
    if (e < NEDGES) {
        int r = row[e];
        int p = atomicAdd(&cursor[r], 1);
        elist[offsets[r] + p] = e;
    }
}

__global__ void prep_graphs(const int* __restrict__ batch, int* __restrict__ starts,
                            int* __restrict__ gcnt)
{
    int i = blockIdx.x * 256 + threadIdx.x;
    if (i < NNODES) {
        int b = batch[i];
        atomicAdd(&gcnt[b], 1);
        if (i == 0 || batch[i - 1] != b) starts[b] = i;
    }
}

__global__ void rowscale(const float* __restrict__ A, int K, float* __restrict__ sc)
{
    int m = blockIdx.x, ln = threadIdx.x;
    float v = 0.f;
    for (int k = ln; k < K; k += 64) v = fmaxf(v, fabsf(A[(size_t)m * K + k]));
    for (int s = 32; s; s >>= 1) v = fmaxf(v, __shfl_xor(v, s));
    if (ln == 0) sc[m] = sc_from_max(v);
}

// merged weight prep (verified round 10-13)
__global__ void prep_wT_all(const float* __restrict__ w_atom, const float* __restrict__ w_bond,
                            const float* __restrict__ conv_w, const float* __restrict__ w_lin,
                            const float* __restrict__ w_out,
                            f16* __restrict__ watomH, f16* __restrict__ watomL,
                            f16* __restrict__ wbondH, f16* __restrict__ wbondL,
                            f16* __restrict__ convH0, f16* __restrict__ convL0,
                            f16* __restrict__ convH1, f16* __restrict__ convL1,
                            f16* __restrict__ convH2, f16* __restrict__ convL2,
                            f16* __restrict__ wlinH, f16* __restrict__ wlinL,
                            f16* __restrict__ woutH, f16* __restrict__ woutL)
{
    int idx = blockIdx.x * 256 + threadIdx.x;
    int krow = idx >> 8, n = idx & 255;
    const float* src; f16* oH; f16* oL; int k;
    if (krow < 128)       { src = w_atom;           oH = watomH; oL = watomL; k = krow; }
    else if (krow < 192)  { src = w_bond;           oH = wbondH; oL = wbondL; k = krow - 128; }
    else if (krow < 448)  { src = conv_w;           oH = convH0; oL = convL0; k = krow - 192; }
    else if (krow < 704)  { src = conv_w + 65536;   oH = convH1; oL = convL1; k = krow - 448; }
    else if (krow < 960)  { src = conv_w + 131072;  oH = convH2; oL = convL2; k = krow - 704; }
    else if (krow < 1728) { src = w_lin;            oH = wlinH;  oL = wlinL;  k = krow - 960; }
    else                  { src = w_out;            oH = woutH;  oL = woutL;  k = krow - 1728; }
    float v = src[(size_t)k * 256 + n] * SB;
    f16 h = (f16)v;
    size_t o = ((size_t)(k >> 5) * 256 + n) * 32 + (k & 31);
    oH[o] = h;
    oL[o] = (f16)(v - (float)h);
}

// GRU weight prep (verified round 2-13)
__global__ void prep_gruW(const float* __restrict__ w_ih, const float* __restrict__ w_hh,
                          const float* __restrict__ b_ih, const float* __restrict__ b_hh,
                          f16* __restrict__ BgH, f16* __restrict__ BgL,
                          float* __restrict__ bias4)
{
    int idx = blockIdx.x * 256 + threadIdx.x;   // 2*512*1024
    int d = idx >> 19;
    int rem = idx & 524287;
    int k = rem >> 10;
    int col = rem & 1023;
    int jj = col >> 2, s = col & 3;
    const float* Wi = w_ih + (size_t)d * 768 * 256;
    const float* Wh = w_hh + (size_t)d * 768 * 256;
    float v;
    if (s == 0)      v = (k < 256) ? Wi[(size_t)jj * 256 + k]         : Wh[(size_t)jj * 256 + (k - 256)];
    else if (s == 1) v = (k < 256) ? Wi[(size_t)(256 + jj) * 256 + k] : Wh[(size_t)(256 + jj) * 256 + (k - 256)];
    else if (s == 2) v = (k < 256) ? Wi[(size_t)(512 + jj) * 256 + k] : 0.f;
    else             v = (k < 256) ? 0.f : Wh[(size_t)(512 + jj) * 256 + (k - 256)];
    v *= SB;
    f16 h = (f16)v;
    size_t o = ((size_t)(d * 16 + (k >> 5)) * 1024 + col) * 32 + (k & 31);
    BgH[o] = h;
    BgL[o] = (f16)(v - (float)h);
    if (k == 0) {
        const float* bi = b_ih + d * 768;
        const float* bh = b_hh + d * 768;
        float bv;
        if (s == 0)      bv = bi[jj] + bh[jj];
        else if (s == 1) bv = bi[256 + jj] + bh[256 + jj];
        else if (s == 2) bv = bi[512 + jj];
        else             bv = bh[512 + jj];
        bias4[d * 1024 + col] = bv;
    }
}

// booster v2 (verified round 10-13)
__global__ void booster(const float* __restrict__ hb_lo, const float* __restrict__ hb_hi,
                        const float* __restrict__ atom_in, float* __restrict__ out,
                        const int* __restrict__ offsets, const int* __restrict__ elist,
                        float* __restrict__ scOut)
{
    const int wv = threadIdx.x >> 6;
    const int n = blockIdx.x * 4 + wv;
    const int ln = threadIdx.x & 63;
    const int b0 = offsets[n], b1 = offsets[n + 1];
    float4 s = {0.f, 0.f, 0.f, 0.f}, m = {0.f, 0.f, 0.f, 0.f};
    for (int p = b0; p < b1; p++) {
        int e = elist[p];
        const float* hb = (e < NNODES) ? (hb_lo + (size_t)e * HH)
                                       : (hb_hi + (size_t)(e - NNODES) * HH);
        float4 v = *(const float4*)(hb + ln * 4);
        s.x += v.x; s.y += v.y; s.z += v.z; s.w += v.w;
        m.x = fmaxf(m.x, v.x); m.y = fmaxf(m.y, v.y);
        m.z = fmaxf(m.z, v.z); m.w = fmaxf(m.w, v.w);
    }
    float4 a = *(const float4*)(atom_in + (size_t)n * HH + ln * 4);
    float4 o;
    o.x = a.x + s.x * m.x; o.y = a.y + s.y * m.y;
    o.z = a.z + s.z * m.z; o.w = a.w + s.w * m.w;
    *(float4*)(out + (size_t)n * HH + ln * 4) = o;
    float v = fmaxf(fmaxf(fabsf(o.x), fabsf(o.y)), fmaxf(fabsf(o.z), fabsf(o.w)));
    for (int t = 32; t; t >>= 1) v = fmaxf(v, __shfl_xor(v, t));
    if (ln == 0) scOut[n] = sc_from_max(v);
}

// h0_init v2 (verified round 10-13)
__global__ void h0_init(const float* __restrict__ h, const int* __restrict__ starts,
                        const int* __restrict__ gcnt, float* __restrict__ hid0,
                        float* __restrict__ scG)
{
    const int wv = threadIdx.x >> 6;
    const int g = blockIdx.x * 4 + wv;
    const int ln = threadIdx.x & 63;
    const int st = starts[g], cn = gcnt[g];
    float4 m = {-INFINITY, -INFINITY, -INFINITY, -INFINITY};
    float4 am = {0.f, 0.f, 0.f, 0.f};
    for (int i = 0; i < cn; i++) {
        float4 v = *(const float4*)(h + (size_t)(st + i) * HH + ln * 4);
        m.x = fmaxf(m.x, v.x); m.y = fmaxf(m.y, v.y);
        m.z = fmaxf(m.z, v.z); m.w = fmaxf(m.w, v.w);
        am.x = fmaxf(am.x, fabsf(v.x)); am.y = fmaxf(am.y, fabsf(v.y));
        am.z = fmaxf(am.z, fabsf(v.z)); am.w = fmaxf(am.w, fabsf(v.w));
    }
    if (cn == 0) { m.x = m.y = m.z = m.w = 0.f; }
    *(float4*)(hid0 + (size_t)g * HH + ln * 4) = m;
    *(float4*)(hid0 + (size_t)GG * HH + (size_t)g * HH + ln * 4) = m;
    float a = fmaxf(fmaxf(am.x, am.y), fmaxf(am.z, am.w));
    for (int t = 32; t; t >>= 1) a = fmaxf(a, __shfl_xor(a, t));
    if (ln == 0) scG[g] = sc_from_max(fmaxf(a + 0.07f, 1.0f));
}

// msgP v2 (verified round 12/13): float4 per thread, 4 graphs per block
__global__ void build_msgP(const float* __restrict__ h, const float* __restrict__ gbias,
                           const int* __restrict__ starts, const int* __restrict__ gcnt,
                           float* __restrict__ msgP)
{
    const int l = blockIdx.x;
    const int g = blockIdx.y * 4 + (threadIdx.x >> 6);
    const int q = threadIdx.x & 63;
    float4 v = {0.f, 0.f, 0.f, 0.f};
    if (l < gcnt[g]) {
        float4 hv = *(const float4*)(h + (size_t)(starts[g] + l) * HH + q * 4);
        float4 bv = *(const float4*)(gbias + q * 4);
        v.x = fmaxf(hv.x + bv.x, 0.f); v.y = fmaxf(hv.y + bv.y, 0.f);
        v.z = fmaxf(hv.z + bv.z, 0.f); v.w = fmaxf(hv.w + bv.w, 0.f);
    }
    *(float4*)(msgP + ((size_t)l * GG + g) * HH + q * 4) = v;
}

// ---------------------------------------------------------------------------
// A-tile element loaders (8 consecutive k of one row)
// ---------------------------------------------------------------------------
template<int MODE>
__device__ __forceinline__ void gemmLoadA(const float* __restrict__ A,
    const float* __restrict__ S0, const float* __restrict__ S1,
    const float* __restrict__ S2, int rI, int cI, int row, int K, int k,
    float va[8])
{
    if constexpr (MODE == 0) {
        const float* p = A + (size_t)row * K + k;
        float4 v0 = *(const float4*)p, v1 = *(const float4*)(p + 4);
        va[0]=v0.x; va[1]=v0.y; va[2]=v0.z; va[3]=v0.w;
        va[4]=v1.x; va[5]=v1.y; va[6]=v1.z; va[7]=v1.w;
    } else if constexpr (MODE == 1) {
        const float* pa = S0 + (size_t)rI * HH + k;
        const float* pb = S1 + (size_t)cI * HH + k;
        float4 a0 = *(const float4*)pa, a1 = *(const float4*)(pa + 4);
        float4 b0 = *(const float4*)pb, b1 = *(const float4*)(pb + 4);
        va[0]=a0.x-b0.x; va[1]=a0.y-b0.y; va[2]=a0.z-b0.z; va[3]=a0.w-b0.w;
        va[4]=a1.x-b1.x; va[5]=a1.y-b1.y; va[6]=a1.z-b1.z; va[7]=a1.w-b1.w;
    } else if constexpr (MODE == 2) {
        const float* S = (k < 256) ? S0 : ((k < 512) ? S1 : S2);
        const float* p = S + (size_t)row * HH + (k & 255);
        float4 v0 = *(const float4*)p, v1 = *(const float4*)(p + 4);
        va[0]=v0.x; va[1]=v0.y; va[2]=v0.z; va[3]=v0.w;
        va[4]=v1.x; va[5]=v1.y; va[6]=v1.z; va[7]=v1.w;
    } else {
        const float* S = (k < 256) ? S0 : S1;
        const float* p = S + (size_t)row * HH + (k & 255);
        float4 v0 = *(const float4*)p, v1 = *(const float4*)(p + 4);
        va[0]=v0.x; va[1]=v0.y; va[2]=v0.z; va[3]=v0.w;
        va[4]=v1.x; va[5]=v1.y; va[6]=v1.z; va[7]=v1.w;
    }
}

// ---------------------------------------------------------------------------
// f16 split MFMA GEMM — EXACT round-11 v3 (best measured: w_lin ~102 us).
// 256 threads, 64x256 tile, A-LDS dbuf, B reg-dbuf 1-deep, 1 barrier/iter.
// ---------------------------------------------------------------------------
template<int MODE, bool RELU, bool SPLITC, bool WSCALE, int NX>
__global__ __launch_bounds__(256, 2) void gemm_f16x3(
    const float* __restrict__ A,
    const float* __restrict__ S0, const float* __restrict__ S1, const float* __restrict__ S2,
    const int* __restrict__ ridx, const int* __restrict__ cidx,
    const f16* __restrict__ BgH, const f16* __restrict__ BgL,
    const float* __restrict__ bias,
    const float* __restrict__ sc0, const float* __restrict__ sc1, const float* __restrict__ sc2,
    float* __restrict__ Clo, float* __restrict__ Chi,
    float* __restrict__ scOut, int K)
{
    __shared__ __align__(16) f16 AhB[2][64 * 40], AlB[2][64 * 40];
    __shared__ float scL[64];
    __shared__ float rmL[64][4];

    const int tid = threadIdx.x;
    const int m0 = blockIdx.x * 64;
    const int arow = tid >> 2, aoct = tid & 3;
    const int w = tid >> 6, lane = tid & 63, lr = lane & 15, lh = lane >> 4;

    if (tid < 64) {
        float sc;
        if constexpr (MODE == 0) sc = sc0[m0 + tid];
        else if constexpr (MODE == 1) {
            int r = ridx[m0 + tid], cc = cidx[m0 + tid];
            sc = fminf(sc0[r], sc1[cc]) * 0.5f;
        } else if constexpr (MODE == 2) {
            sc = fminf(fminf(sc0[m0 + tid], sc1[m0 + tid]), sc2[m0 + tid]);
        } else {
            sc = sc0[cidx[m0 + tid]];
        }
        scL[tid] = sc;
    }
    int rI = 0, cI = 0;
    if constexpr (MODE == 1) { rI = ridx[m0 + arow]; cI = cidx[m0 + arow]; }
    __syncthreads();
    const float myS = scL[arow];
    const int nIter = K >> 5;

    // ---- prologue: A(0) -> buf0; B(0) -> regs
    {
        float va0[8];
        gemmLoadA<MODE>(A, S0, S1, S2, rI, cI, m0 + arow, K, aoct * 8, va0);
        f16x8 hi, lo;
#pragma unroll
        for (int e = 0; e < 8; e++) {
            float a = va0[e] * myS;
            f16 h = (f16)a;
            hi[e] = h;
            if constexpr (NX == 3) lo[e] = (f16)(a - (float)h);
        }
        *(f16x8*)&AhB[0][arow * 40 + aoct * 8] = hi;
        if constexpr (NX == 3) *(f16x8*)&AlB[0][arow * 40 + aoct * 8] = lo;
    }
    f16x8 fbh[4], fbl[4];
#pragma unroll
    for (int j = 0; j < 4; j++) {
        size_t o = (size_t)(w * 64 + j * 16 + lr) * 32 + lh * 8;
        fbh[j] = *(const f16x8*)(BgH + o);
        if constexpr (NX == 3) fbl[j] = *(const f16x8*)(BgL + o);
    }
    __syncthreads();

    f32x4 acc[4][4] = {};
    for (int kb = 0; kb < nIter; kb++) {
        const f16* AhC = AhB[kb & 1];
        const f16* AlC = AlB[kb & 1];
        float va[8];
        f16x8 nbh[4], nbl[4];
        if (kb + 1 < nIter) {
            gemmLoadA<MODE>(A, S0, S1, S2, rI, cI, m0 + arow, K, (kb + 1) * 32 + aoct * 8, va);
#pragma unroll
            for (int j = 0; j < 4; j++) {
                size_t o = ((size_t)(kb + 1) * 256 + (w * 64 + j * 16 + lr)) * 32 + lh * 8;
                nbh[j] = *(const f16x8*)(BgH + o);
                if constexpr (NX == 3) nbl[j] = *(const f16x8*)(BgL + o);
            }
        }
        f16x8 fah[4], fal[4];
#pragma unroll
        for (int i = 0; i < 4; i++) {
            fah[i] = *(const f16x8*)&AhC[(i * 16 + lr) * 40 + lh * 8];
            if constexpr (NX == 3) fal[i] = *(const f16x8*)&AlC[(i * 16 + lr) * 40 + lh * 8];
        }
#pragma unroll
        for (int j = 0; j < 4; j++) {
            if constexpr (NX == 3) {
#pragma unroll
                for (int i = 0; i < 4; i++) {
                    acc[i][j] = MFMA16(fah[i], fbh[j], acc[i][j]);
                    acc[i][j] = MFMA16(fah[i], fbl[j], acc[i][j]);
                    acc[i][j] = MFMA16(fal[i], fbh[j], acc[i][j]);
                }
            } else {
#pragma unroll
                for (int i = 0; i < 4; i++)
                    acc[i][j] = MFMA16(fah[i], fbh[j], acc[i][j]);
            }
        }
        if (kb + 1 < nIter) {
            f16x8 hi, lo;
#pragma unroll
            for (int e = 0; e < 8; e++) {
                float a = va[e] * myS;
                f16 h = (f16)a;
                hi[e] = h;
                if constexpr (NX == 3) lo[e] = (f16)(a - (float)h);
            }
            f16* AhN = AhB[(kb + 1) & 1];
            f16* AlN = AlB[(kb + 1) & 1];
            *(f16x8*)&AhN[arow * 40 + aoct * 8] = hi;
            if constexpr (NX == 3) *(f16x8*)&AlN[arow * 40 + aoct * 8] = lo;
#pragma unroll
            for (int j = 0; j < 4; j++) {
                fbh[j] = nbh[j];
                if constexpr (NX == 3) fbl[j] = nbl[j];
            }
        }
        __syncthreads();
    }

    float rm[4][4];
#pragma unroll
    for (int i = 0; i < 4; i++)
#pragma unroll
        for (int e = 0; e < 4; e++) rm[i][e] = 0.f;
#pragma unroll
    for (int i = 0; i < 4; i++) {
#pragma unroll
        for (int e = 0; e < 4; e++) {
            int ml = i * 16 + lh * 4 + e;
            int m = m0 + ml;
            float inv = DSB / scL[ml];
            float* Cb;
            if constexpr (SPLITC)
                Cb = (m < NNODES) ? (Clo + (size_t)m * HH) : (Chi + (size_t)(m - NNODES) * HH);
            else
                Cb = Clo + (size_t)m * HH;
#pragma unroll
            for (int j = 0; j < 4; j++) {
                int n = w * 64 + j * 16 + lr;
                float v = acc[i][j][e] * inv + bias[n];
                if constexpr (RELU) v = fmaxf(v, 0.f);
                Cb[n] = v;
                if constexpr (WSCALE) rm[i][e] = fmaxf(rm[i][e], fabsf(v));
            }
        }
    }
    if constexpr (WSCALE) {
#pragma unroll
        for (int i = 0; i < 4; i++)
#pragma unroll
            for (int e = 0; e < 4; e++) {
                float v = rm[i][e];
                v = fmaxf(v, __shfl_xor(v, 1));
                v = fmaxf(v, __shfl_xor(v, 2));
                v = fmaxf(v, __shfl_xor(v, 4));
                v = fmaxf(v, __shfl_xor(v, 8));
                if (lr == 0) rmL[i * 16 + lh * 4 + e][w] = v;
            }
        __syncthreads();
        if (tid < 64)
            scOut[m0 + tid] = sc_from_max(fmaxf(fmaxf(rmL[tid][0], rmL[tid][1]),
                                                fmaxf(rmL[tid][2], rmL[tid][3])));
    }
}

// ---------------------------------------------------------------------------
// GRU step v8 (verified round 12/13): 512 threads, 64g x 128c, grid 256,
// 2-deep A prefetch, reg-dbuf B, LDS-dbuf A, 1 barrier/window.
// ---------------------------------------------------------------------------
__global__ __launch_bounds__(512) void gru_step_f16(
    const float* __restrict__ msgP, const f16* __restrict__ BgH, const f16* __restrict__ BgL,
    const float* __restrict__ bias4, const float* __restrict__ hidC, float* __restrict__ hidN,
    const float* __restrict__ scG, const int* __restrict__ starts, const int* __restrict__ gcnt,
    float* __restrict__ outF, float* __restrict__ outB, int t)
{
    __shared__ __align__(16) char smemraw[36864];
    float* Cs = (float*)smemraw;
    __shared__ float scL[64];

    const int tid = threadIdx.x;
    const int id = blockIdx.x;
    const int c = id & 7, d = (id >> 3) & 1, gt = id >> 4;
    const int g0 = gt * 64;
    const int l = d ? (LL - 1 - t) : t;
    const float* hidCd = hidC + (size_t)d * GG * HH;
    float* hidNd = hidN + (size_t)d * GG * HH;

    if (tid < 64) scL[tid] = scG[g0 + tid];
    __syncthreads();

    const int arow = tid >> 3, akoct = tid & 7;
    const float myS = scL[arow];
    const int w = tid >> 6;
    const int wg = w >> 2, wc = w & 3;
    const int lane = tid & 63, lr = lane & 15, lh = lane >> 4;

    f16* Ah0 = (f16*)smemraw;
    f16* Al0 = Ah0 + 4608;
    f16* Ah1 = Al0 + 4608;
    f16* Al1 = Ah1 + 4608;

    {
        const float* p = msgP + ((size_t)l * GG + g0 + arow) * HH + akoct * 8;
        float4 v0 = *(const float4*)p, v1 = *(const float4*)(p + 4);
        float va0[8] = {v0.x, v0.y, v0.z, v0.w, v1.x, v1.y, v1.z, v1.w};
        f16x8 hi, lo;
#pragma unroll
        for (int e = 0; e < 8; e++) {
            float a = va0[e] * myS;
            f16 h = (f16)a;
            hi[e] = h;
            lo[e] = (f16)(a - (float)h);
        }
        *(f16x8*)&Ah0[arow * 72 + akoct * 8] = hi;
        *(f16x8*)&Al0[arow * 72 + akoct * 8] = lo;
    }
    float va[8];
    {
        const float* p = msgP + ((size_t)l * GG + g0 + arow) * HH + 64 + akoct * 8;
        float4 v0 = *(const float4*)p, v1 = *(const float4*)(p + 4);
        va[0]=v0.x; va[1]=v0.y; va[2]=v0.z; va[3]=v0.w;
        va[4]=v1.x; va[5]=v1.y; va[6]=v1.z; va[7]=v1.w;
    }
    f16x8 fbh[2][2], fbl[2][2];
#pragma unroll
    for (int ks = 0; ks < 2; ks++) {
        size_t kbase = (size_t)(d * 16 + ks) * 1024;
#pragma unroll
        for (int j = 0; j < 2; j++) {
            size_t o = (kbase + (c * 128 + wc * 32 + j * 16 + lr)) * 32 + lh * 8;
            fbh[ks][j] = *(const f16x8*)(BgH + o);
            fbl[ks][j] = *(const f16x8*)(BgL + o);
        }
    }
    __syncthreads();

    f32x4 acc[2][2] = {};
#pragma unroll
    for (int win = 0; win < 8; win++) {
        f16* AhC = (win & 1) ? Ah1 : Ah0;
        f16* AlC = (win & 1) ? Al1 : Al0;
        f16* AhN = (win & 1) ? Ah0 : Ah1;
        f16* AlN = (win & 1) ? Al0 : Al1;

        float nva[8];
        if (win + 2 < 8) {
            int k = (win + 2) * 64 + akoct * 8;
            const float* p = (k < 256)
                ? msgP + ((size_t)l * GG + g0 + arow) * HH + k
                : hidCd + (size_t)(g0 + arow) * HH + (k - 256);
            float4 v0 = *(const float4*)p, v1 = *(const float4*)(p + 4);
            nva[0]=v0.x; nva[1]=v0.y; nva[2]=v0.z; nva[3]=v0.w;
            nva[4]=v1.x; nva[5]=v1.y; nva[6]=v1.z; nva[7]=v1.w;
        }
        f16x8 nbh[2][2], nbl[2][2];
        if (win + 1 < 8) {
#pragma unroll
            for (int ks = 0; ks < 2; ks++) {
                size_t kbase = (size_t)(d * 16 + (win + 1) * 2 + ks) * 1024;
#pragma unroll
                for (int j = 0; j < 2; j++) {
                    size_t o = (kbase + (c * 128 + wc * 32 + j * 16 + lr)) * 32 + lh * 8;
                    nbh[ks][j] = *(const f16x8*)(BgH + o);
                    nbl[ks][j] = *(const f16x8*)(BgL + o);
                }
            }
        }
#pragma unroll
        for (int ks = 0; ks < 2; ks++) {
            f16x8 fah[2], fal[2];
#pragma unroll
            for (int i = 0; i < 2; i++) {
                fah[i] = *(const f16x8*)&AhC[(wg * 32 + i * 16 + lr) * 72 + ks * 32 + lh * 8];
                fal[i] = *(const f16x8*)&AlC[(wg * 32 + i * 16 + lr) * 72 + ks * 32 + lh * 8];
            }
#pragma unroll
            for (int j = 0; j < 2; j++) {
#pragma unroll
                for (int i = 0; i < 2; i++) {
                    acc[i][j] = MFMA16(fah[i], fbh[ks][j], acc[i][j]);
                    acc[i][j] = MFMA16(fah[i], fbl[ks][j], acc[i][j]);
                    acc[i][j] = MFMA16(fal[i], fbh[ks][j], acc[i][j]);
                }
            }
        }
        if (win + 1 < 8) {
            f16x8 hi, lo;
#pragma unroll
            for (int e = 0; e < 8; e++) {
                float a = va[e] * myS;
                f16 h = (f16)a;
                hi[e] = h;
                lo[e] = (f16)(a - (float)h);
            }
            *(f16x8*)&AhN[arow * 72 + akoct * 8] = hi;
            *(f16x8*)&AlN[arow * 72 + akoct * 8] = lo;
        }
        if (win + 2 < 8) {
#pragma unroll
            for (int e = 0; e < 8; e++) va[e] = nva[e];
        }
        if (win + 1 < 8) {
#pragma unroll
            for (int ks = 0; ks < 2; ks++)
#pragma unroll
                for (int j = 0; j < 2; j++) {
                    fbh[ks][j] = nbh[ks][j];
                    fbl[ks][j] = nbl[ks][j];
                }
        }
        __syncthreads();
    }

#pragma unroll
    for (int i = 0; i < 2; i++) {
#pragma unroll
        for (int e = 0; e < 4; e++) {
            int ml = wg * 32 + i * 16 + lh * 4 + e;
            float inv = DSB / scL[ml];
#pragma unroll
            for (int j = 0; j < 2; j++)
                Cs[ml * 132 + wc * 32 + j * 16 + lr] = acc[i][j][e] * inv;
        }
    }
    __syncthreads();

    const float* b4 = bias4 + d * 1024;
    const int jl = tid & 31;
    const int J  = c * 32 + jl;
    const int gbase = (tid >> 5) * 4;
    const float bb0 = b4[4 * J + 0], bb1 = b4[4 * J + 1];
    const float bb2 = b4[4 * J + 2], bb3 = b4[4 * J + 3];
    float* o = d ? outB : outF;
#pragma unroll
    for (int i = 0; i < 4; i++) {
        int gl = gbase + i;
        int g = g0 + gl;
        f32x4 gv = *(const f32x4*)&Cs[gl * 132 + jl * 4];
        float r = 1.f / (1.f + expf(-(gv[0] + bb0)));
        float z = 1.f / (1.f + expf(-(gv[1] + bb1)));
        float nn = tanhf(gv[2] + bb2 + r * (gv[3] + bb3));
        float hp = hidCd[(size_t)g * HH + J];
        float hnew = (1.f - z) * nn + z * hp;
        hidNd[(size_t)g * HH + J] = hnew;
        if (l < gcnt[g]) o[(size_t)(starts[g] + l) * HH + J] = hnew;
    }
}

__global__ void fill_sentinel(float* __restrict__ out, float v)
{
    size_t idx = (size_t)blockIdx.x * 256 + threadIdx.x;
    out[idx] = v;
}

// ---------------------------------------------------------------------------
// Workspace layout identical to round 3-13 (verified).
// ---------------------------------------------------------------------------
extern "C" void kernel_launch(void* const* d_in, const int* in_sizes, int n_in,
                              void* d_out, int out_size, void* d_ws, size_t ws_size,
                              hipStream_t stream)
{
    (void)in_sizes; (void)n_in; (void)out_size;
    const float* x         = (const float*)d_in[0];
    const float* edge_attr = (const float*)d_in[1];
    const int*   eidx      = (const int*)d_in[2];
    const int*   batch     = (const int*)d_in[3];
    const float* w_atom    = (const float*)d_in[4];
    const float* b_atom    = (const float*)d_in[5];
    const float* w_bond    = (const float*)d_in[6];
    const float* b_bond    = (const float*)d_in[7];
    const float* conv_w    = (const float*)d_in[8];
    const float* conv_b    = (const float*)d_in[9];
    const float* w_lin     = (const float*)d_in[10];
    const float* b_lin     = (const float*)d_in[11];
    const float* gru_bias  = (const float*)d_in[12];
    const float* w_ih      = (const float*)d_in[13];
    const float* w_hh      = (const float*)d_in[14];
    const float* b_ih      = (const float*)d_in[15];
    const float* b_hh      = (const float*)d_in[16];
    const float* w_out     = (const float*)d_in[17];
    const float* b_out     = (const float*)d_in[18];

    const int* row = eidx;
    const int* col = eidx + NEDGES;

    const size_t NH = (size_t)NNODES * HH;

    float* W   = (float*)d_ws;
    float* W0  = W;
    float* W1  = W + NH;
    float* W1h = W + 2 * NH;
    float* W2  = W + 3 * NH;
    float* DO  = (float*)d_out;

    size_t off = 4 * NH;
    int* counts  = (int*)(W + off);      off += NNODES;
    int* cursor  = (int*)(W + off);      off += NNODES;
    int* gcnt    = (int*)(W + off);      off += GG;
    int* starts  = (int*)(W + off);      off += GG;
    int* offsets = (int*)(W + off);      off += NNODES + 1;
    int* elist   = (int*)(W + off);      off += NEDGES;
    float* scX    = W + off;             off += NNODES;
    float* scEA   = W + off;             off += NEDGES;
    float* scHbA  = W + off;             off += NEDGES;
    float* scHbB  = W + off;             off += NEDGES;
    float* scAtom = W + off;             off += NNODES;
    float* scAggr = W + off;             off += NNODES;
    float* scXp   = W + off;             off += NNODES;
    float* scGru  = W + off;             off += GG;
    off = (off + 3) & ~(size_t)3;
    f16* fp = (f16*)(W + off);
    f16* watomH = fp;                     fp += 4 * 256 * 32;
    f16* watomL = fp;                     fp += 4 * 256 * 32;
    f16* wbondH = fp;                     fp += 2 * 256 * 32;
    f16* wbondL = fp;                     fp += 2 * 256 * 32;
    f16* convH[3]; f16* convL[3];
    for (int i = 0; i < 3; i++) { convH[i] = fp; fp += 8 * 256 * 32; convL[i] = fp; fp += 8 * 256 * 32; }
    f16* wlinH = fp;                      fp += 24 * 256 * 32;
    f16* wlinL = fp;                      fp += 24 * 256 * 32;
    f16* woutH = fp;                      fp += 16 * 256 * 32;
    f16* woutL = fp;                      fp += 16 * 256 * 32;

    const size_t NEED = (char*)fp - (char*)d_ws;
    if (ws_size < NEED) {
        fill_sentinel<<<(int)(NH / 256), 256, 0, stream>>>((float*)d_out, (float)ws_size);
        return;
    }

    // d_out overlay (dead between final booster and final GEMM)
    float* hid0  = DO;
    float* hid1  = DO + 2 * (size_t)GG * HH;
    float* bias4 = DO + 4 * (size_t)GG * HH;
    f16* BgH = (f16*)(bias4 + 2048);
    f16* BgL = BgH + (size_t)2 * 16 * 1024 * 32;

    hipMemsetAsync(counts, 0, (size_t)(2 * NNODES + 2 * GG) * sizeof(int), stream);
    prep_graphs<<<(NNODES + 255) / 256, 256, 0, stream>>>(batch, starts, gcnt);
    csr_count<<<(NEDGES + 255) / 256, 256, 0, stream>>>(row, counts);
    scan_offsets<<<1, 1024, 0, stream>>>(counts, offsets);
    csr_fill<<<(NEDGES + 255) / 256, 256, 0, stream>>>(row, offsets, cursor, elist);

    rowscale<<<NNODES, 64, 0, stream>>>(x, 128, scX);
    rowscale<<<NEDGES, 64, 0, stream>>>(edge_attr, 64, scEA);

    prep_wT_all<<<2240, 256, 0, stream>>>(w_atom, w_bond, conv_w, w_lin, w_out,
        watomH, watomL, wbondH, wbondL, convH[0], convL[0], convH[1], convL[1],
        convH[2], convL[2], wlinH, wlinL, woutH, woutL);

    // x_proj = relu(x @ w_atom + b_atom) -> W0, scAtom
    gemm_f16x3<0, true, false, true, 3><<<NNODES / 64, 256, 0, stream>>>(
        x, nullptr, nullptr, nullptr, nullptr, nullptr, watomH, watomL, b_atom,
        scX, nullptr, nullptr, W0, nullptr, scAtom, 128);
    // bondA = relu(edge_attr @ w_bond + b_bond) -> (W1, W1h), scHbA
    gemm_f16x3<0, true, true, true, 3><<<NEDGES / 64, 256, 0, stream>>>(
        edge_attr, nullptr, nullptr, nullptr, nullptr, nullptr, wbondH, wbondL, b_bond,
        scEA, nullptr, nullptr, W1, W1h, scHbA, 64);

    float* cur_lo = W1; float* cur_hi = W1h; float* cur_sc = scHbA;
    float* nxt_lo = W2; float* nxt_hi = DO;  float* nxt_sc = scHbB;
    for (int i = 0; i < 3; i++) {
        booster<<<NNODES / 4, 256, 0, stream>>>(cur_lo, cur_hi, W0, W0, offsets, elist, scAtom);
        gemm_f16x3<1, true, true, true, 3><<<NEDGES / 64, 256, 0, stream>>>(
            nullptr, W0, cur_lo, nullptr, row, col, convH[i], convL[i],
            conv_b + (size_t)i * HH, scAtom, cur_sc, nullptr, nxt_lo, nxt_hi, nxt_sc, 256);
        float* t0 = cur_lo; cur_lo = nxt_lo; nxt_lo = t0;
        float* t1 = cur_hi; cur_hi = nxt_hi; nxt_hi = t1;
        float* t2 = cur_sc; cur_sc = nxt_sc; nxt_sc = t2;
    }
    // aggr = h_atom + booster(bondB) -> W1 (bondA dead)
    booster<<<NNODES / 4, 256, 0, stream>>>(cur_lo, cur_hi, W0, W1, offsets, elist, scAggr);
    // recompute x_proj -> W1h
    gemm_f16x3<0, true, false, true, 3><<<NNODES / 64, 256, 0, stream>>>(
        x, nullptr, nullptr, nullptr, nullptr, nullptr, watomH, watomL, b_atom,
        scX, nullptr, nullptr, W1h, nullptr, scXp, 128);
    // h = concat(aggr, h_atom, x_proj) @ w_lin + b_lin -> W2
    gemm_f16x3<2, false, false, false, 3><<<NNODES / 64, 256, 0, stream>>>(
        nullptr, W1, W0, W1h, nullptr, nullptr, wlinH, wlinL, b_lin,
        scAggr, scAtom, scXp, W2, nullptr, nullptr, 768);

    // GRU prep (DO bond rows dead now)
    h0_init<<<GG / 4, 256, 0, stream>>>(W2, starts, gcnt, hid0, scGru);
    build_msgP<<<dim3(LL, GG / 4), 256, 0, stream>>>(W2, gru_bias, starts, gcnt, W1h);
    prep_gruW<<<(2 * 512 * 1024) / 256, 256, 0, stream>>>(w_ih, w_hh, b_ih, b_hh, BgH, BgL, bias4);

    for (int t = 0; t < LL; t++) {
        float* hc = (t & 1) ? hid1 : hid0;
        float* hx = (t & 1) ? hid0 : hid1;
        gru_step_f16<<<256, 512, 0, stream>>>(W1h, BgH, BgL, bias4, hc, hx,
                                              scGru, starts, gcnt, W0, W1, t);
    }

    // out = relu(concat(outF, outB) @ w_out + b_out), pure f16 (NX=1)
    gemm_f16x3<3, true, false, false, 1><<<NNODES / 64, 256, 0, stream>>>(
        nullptr, W0, W1, nullptr, nullptr, batch, woutH, nullptr, b_out,
        scGru, nullptr, nullptr, (float*)d_out, nullptr, nullptr, 512);
}